// Round 3
// baseline (144.853 us; speedup 1.0000x reference)
//
#include <hip/hip_runtime.h>

// Problem constants: B=2, L=16, N=10000, FIN=8, H=64, P=12, E=80000, K=3
#define NN   10000
#define LL   16
#define FINC 8
#define HH   64
#define PP   12
#define EE   80000
#define BLH  256   // (b,lp,h) = 2*2*64 — only l=14,15 feed out[:,:,-1] (K=3, pad=1)
#define CAP  64    // per-row edge bucket capacity; E/N = 8, P(deg>64) ~ 0

// ---------------------------------------------------------------------------
// k1: input projection at l in {14,15} + zero deg + zero-pad this node's bucket.
// hsmall[n*256 + (b*2+lp)*64 + h] = relu(b_in[h] + sum_f x[b,14+lp,n,f]*W_in[f,h])
// ---------------------------------------------------------------------------
__global__ __launch_bounds__(256) void k1_input_proj(
        const float* __restrict__ x, const float* __restrict__ W_in,
        const float* __restrict__ b_in, float* __restrict__ hsmall,
        int* __restrict__ deg, int2* __restrict__ bucket) {
    __shared__ float xs[32];          // 4 (b,lp) groups * 8 features
    __shared__ float ws[FINC * HH];   // 512
    __shared__ float bs[HH];
    const int n = blockIdx.x;
    const int t = threadIdx.x;  // 0..255
    ws[t]       = W_in[t];
    ws[t + 256] = W_in[t + 256];
    if (t < HH) bs[t] = b_in[t];
    if (t == 0) deg[n] = 0;
    if (t < CAP) bucket[(size_t)n * CAP + t] = make_int2(0, 0);  // {col=0, val=0.0}
    if (t < 32) {
        int bl = t >> 3;              // (b*2+lp)
        int f  = t & 7;
        int b  = bl >> 1, lp = bl & 1;
        xs[t] = x[(((size_t)(b * LL + 14 + lp)) * NN + n) * FINC + f];
    }
    __syncthreads();
    const int h  = t & 63;
    const int bl = t >> 6;
    float acc = bs[h];
#pragma unroll
    for (int f = 0; f < FINC; ++f)
        acc = fmaf(xs[bl * 8 + f], ws[f * HH + h], acc);
    hsmall[(size_t)n * BLH + t] = fmaxf(acc, 0.f);
}

// ---------------------------------------------------------------------------
// k2: one-pass bucketed CSR build.
// ---------------------------------------------------------------------------
__global__ __launch_bounds__(256) void k2_build(
        const int* __restrict__ row, const int* __restrict__ col,
        const float* __restrict__ vals, int* __restrict__ deg,
        int2* __restrict__ bucket) {
    int e = blockIdx.x * 256 + threadIdx.x;
    if (e < EE) {
        int r = row[e];
        int pos = atomicAdd(&deg[r], 1);
        if (pos < CAP)
            bucket[(size_t)r * CAP + pos] = make_int2(col[e], __float_as_int(vals[e]));
    }
}

// ---------------------------------------------------------------------------
// k3: gather-aggregate, zero LDS, max occupancy + MLP.
// One wave per node. Metadata: one coalesced 512B load (bucket row is
// zero-padded), broadcast via shfl. Row loads issued 8-deep independent.
// h2[n][j] = relu( sum_e val_e * hsmall[col_e][j] )
// ---------------------------------------------------------------------------
__global__ __launch_bounds__(256) void k3_gather(
        const float* __restrict__ hsmall, const int* __restrict__ deg,
        const int2* __restrict__ bucket, float* __restrict__ h2) {
    const int wave = threadIdx.x >> 6;
    const int lane = threadIdx.x & 63;
    const int n = blockIdx.x * 4 + wave;
    const int dn  = min(deg[n], CAP);
    const int dnp = (dn + 7) & ~7;                    // padded entries are {0, 0.0}
    const int2 meta = bucket[(size_t)n * CAP + lane]; // coalesced, always valid

    float4 acc = make_float4(0.f, 0.f, 0.f, 0.f);
    for (int i = 0; i < dnp; i += 8) {
        int   c[8];
        float v[8];
#pragma unroll
        for (int j = 0; j < 8; ++j) {
            c[j] = __shfl(meta.x, i + j);
            v[j] = __int_as_float(__shfl(meta.y, i + j));
        }
        float4 hv[8];
#pragma unroll
        for (int j = 0; j < 8; ++j)
            hv[j] = *(const float4*)&hsmall[(size_t)c[j] * BLH + lane * 4];
#pragma unroll
        for (int j = 0; j < 8; ++j) {
            acc.x = fmaf(v[j], hv[j].x, acc.x);
            acc.y = fmaf(v[j], hv[j].y, acc.y);
            acc.z = fmaf(v[j], hv[j].z, acc.z);
            acc.w = fmaf(v[j], hv[j].w, acc.w);
        }
    }
    float4 r = make_float4(fmaxf(acc.x, 0.f), fmaxf(acc.y, 0.f),
                           fmaxf(acc.z, 0.f), fmaxf(acc.w, 0.f));
    *(float4*)&h2[(size_t)n * BLH + lane * 4] = r;
}

// ---------------------------------------------------------------------------
// k4: TCN last position (taps 0,1; tap 2 hits zero-pad) + ReLU + W_out.
// 512 blocks x 256 threads; 2 nodes per iteration; Wp staged once per block
// with fully coalesced linear reads of W_tcn.
// ---------------------------------------------------------------------------
__global__ __launch_bounds__(256) void k4_head(
        const float* __restrict__ h2, const float* __restrict__ W_tcn,
        const float* __restrict__ b_tcn, const float* __restrict__ W_out,
        const float* __restrict__ b_out, float* __restrict__ y) {
    __shared__ float wlds[2 * HH * HH];  // [(i*64+o)*2 + k] = W_tcn[o,i,k], 32 KB
    __shared__ float Wo[HH * PP];        // 3 KB
    __shared__ float s[2][BLH];          // two nodes' aggregated vectors, 2 KB
    __shared__ float hl[2][2 * HH];      // 1 KB
    const int t = threadIdx.x;

    // coalesced linear staging of W_tcn (12288 floats), scatter into wlds
    for (int f = t; f < 3 * HH * HH; f += 256) {
        int k = f % 3;
        if (k < 2) {
            int o = f / (HH * 3);
            int i = (f % (HH * 3)) / 3;
            wlds[(i * HH + o) * 2 + k] = W_tcn[f];
        }
    }
    for (int idx = t; idx < HH * PP; idx += 256) Wo[idx] = W_out[idx];
    __syncthreads();

    const int node = t >> 7;        // 0/1 within the pair
    const int bo   = t & 127;
    const int b    = bo >> 6, o = bo & 63;
    const float bt = b_tcn[o];

    for (int pair = blockIdx.x; pair < NN / 2; pair += gridDim.x) {
        const int n0 = pair * 2;
        // coalesced load of both nodes' vectors (512 floats)
        s[0][t]       = h2[(size_t)n0 * BLH + t];
        s[1][t]       = h2[(size_t)n0 * BLH + 256 + t];
        __syncthreads();

        // h_last[node][b][o] = relu(bt + sum_i W0[o,i]*s[node][b*128+i]
        //                                + W1[o,i]*s[node][b*128+64+i])
        float a0 = 0.f, a1 = 0.f;
#pragma unroll 8
        for (int i = 0; i < HH; ++i) {
            float2 w = *(const float2*)&wlds[(i * HH + o) * 2];
            a0 = fmaf(w.x, s[node][b * 128 + i], a0);
            a1 = fmaf(w.y, s[node][b * 128 + 64 + i], a1);
        }
        hl[node][bo] = fmaxf(bt + a0 + a1, 0.f);
        __syncthreads();

        // y[(b*P+p)*N + n] : 48 active threads (2 nodes x 2 b x 12 p)
        if (t < 48) {
            int nd = t / 24, r = t % 24, bb = r / PP, p = r % PP;
            float yy = b_out[p];
#pragma unroll 8
            for (int oo = 0; oo < HH; ++oo)
                yy = fmaf(hl[nd][bb * HH + oo], Wo[oo * PP + p], yy);
            y[((size_t)(bb * PP + p)) * NN + (n0 + nd)] = yy;
        }
        __syncthreads();
    }
}

// ---------------------------------------------------------------------------
extern "C" void kernel_launch(void* const* d_in, const int* in_sizes, int n_in,
                              void* d_out, int out_size, void* d_ws, size_t ws_size,
                              hipStream_t stream) {
    const float* x     = (const float*)d_in[0];
    const int*   row   = (const int*)d_in[1];
    const int*   col   = (const int*)d_in[2];
    const float* vals  = (const float*)d_in[3];
    const float* W_in  = (const float*)d_in[4];
    const float* b_in  = (const float*)d_in[5];
    const float* W_tcn = (const float*)d_in[6];
    const float* b_tcn = (const float*)d_in[7];
    const float* W_out = (const float*)d_in[8];
    const float* b_out = (const float*)d_in[9];
    float* y = (float*)d_out;

    char* ws = (char*)d_ws;
    float* hsmall = (float*)(ws);                    // 10,240,000 B
    int*   deg    = (int*)(ws + 10240000);           //     40,000 B
    int2*  bucket = (int2*)(ws + 10280000);          //  5,120,000 B
    float* h2     = (float*)(ws + 15400000);         // 10,240,000 B

    k1_input_proj<<<NN, 256, 0, stream>>>(x, W_in, b_in, hsmall, deg, bucket);
    k2_build<<<(EE + 255) / 256, 256, 0, stream>>>(row, col, vals, deg, bucket);
    k3_gather<<<NN / 4, 256, 0, stream>>>(hsmall, deg, bucket, h2);
    k4_head<<<512, 256, 0, stream>>>(h2, W_tcn, b_tcn, W_out, b_out, y);
}

// Round 5
// 127.757 us; speedup vs baseline: 1.1338x; 1.1338x over previous
//
#include <hip/hip_runtime.h>

// Problem constants: B=2, L=16, N=10000, FIN=8, H=64, P=12, E=80000, K=3
#define NN   10000
#define LL   16
#define FINC 8
#define HH   64
#define PP   12
#define EE   80000
#define BLH  256   // (b,lp,h) = 2*2*64 — only l=14,15 feed out[:,:,-1] (K=3, pad=1)
#define CAP  64    // per-row edge bucket capacity; E/N = 8, P(deg>64) ~ 0

// ---------------------------------------------------------------------------
// k1: input projection at l in {14,15} + zero deg + zero-pad this node's bucket.
// ---------------------------------------------------------------------------
__global__ __launch_bounds__(256) void k1_input_proj(
        const float* __restrict__ x, const float* __restrict__ W_in,
        const float* __restrict__ b_in, float* __restrict__ hsmall,
        int* __restrict__ deg, int2* __restrict__ bucket) {
    __shared__ float xs[32];
    __shared__ float ws[FINC * HH];
    __shared__ float bs[HH];
    const int n = blockIdx.x;
    const int t = threadIdx.x;
    ws[t]       = W_in[t];
    ws[t + 256] = W_in[t + 256];
    if (t < HH) bs[t] = b_in[t];
    if (t == 0) deg[n] = 0;
    if (t < CAP) bucket[(size_t)n * CAP + t] = make_int2(0, 0);
    if (t < 32) {
        int bl = t >> 3, f = t & 7;
        int b = bl >> 1, lp = bl & 1;
        xs[t] = x[(((size_t)(b * LL + 14 + lp)) * NN + n) * FINC + f];
    }
    __syncthreads();
    const int h  = t & 63;
    const int bl = t >> 6;
    float acc = bs[h];
#pragma unroll
    for (int f = 0; f < FINC; ++f)
        acc = fmaf(xs[bl * 8 + f], ws[f * HH + h], acc);
    hsmall[(size_t)n * BLH + t] = fmaxf(acc, 0.f);
}

// ---------------------------------------------------------------------------
// k2: bucketed CSR build + pack W_tcn taps {0,1} into Wt[k][o] (k = lp*64+i).
// ---------------------------------------------------------------------------
__global__ __launch_bounds__(256) void k2_build(
        const int* __restrict__ row, const int* __restrict__ col,
        const float* __restrict__ vals, int* __restrict__ deg,
        int2* __restrict__ bucket, const float* __restrict__ W_tcn,
        float* __restrict__ Wt) {
    int e = blockIdx.x * 256 + threadIdx.x;
    if (e < EE) {
        int r = row[e];
        int pos = atomicAdd(&deg[r], 1);
        if (pos < CAP)
            bucket[(size_t)r * CAP + pos] = make_int2(col[e], __float_as_int(vals[e]));
    } else if (e < EE + 3 * HH * HH) {
        int f = e - EE;                 // linear index into W_tcn [o][i][k3]
        int kk = f % 3;
        if (kk < 2) {
            int o = f / (HH * 3);
            int i = (f / 3) % HH;
            Wt[(kk * HH + i) * HH + o] = W_tcn[f];
        }
    }
}

// ---------------------------------------------------------------------------
// k3: gather-aggregate, zero LDS. One wave per node; metadata via one
// coalesced 512B load + shfl broadcast; 8 independent row loads in flight.
// ---------------------------------------------------------------------------
__global__ __launch_bounds__(256) void k3_gather(
        const float* __restrict__ hsmall, const int* __restrict__ deg,
        const int2* __restrict__ bucket, float* __restrict__ h2) {
    const int wave = threadIdx.x >> 6;
    const int lane = threadIdx.x & 63;
    const int n = blockIdx.x * 4 + wave;
    const int dn  = min(deg[n], CAP);
    const int dnp = (dn + 7) & ~7;
    const int2 meta = bucket[(size_t)n * CAP + lane];

    float4 acc = make_float4(0.f, 0.f, 0.f, 0.f);
    for (int i = 0; i < dnp; i += 8) {
        int   c[8];
        float v[8];
#pragma unroll
        for (int j = 0; j < 8; ++j) {
            c[j] = __shfl(meta.x, i + j);
            v[j] = __int_as_float(__shfl(meta.y, i + j));
        }
        float4 hv[8];
#pragma unroll
        for (int j = 0; j < 8; ++j)
            hv[j] = *(const float4*)&hsmall[(size_t)c[j] * BLH + lane * 4];
#pragma unroll
        for (int j = 0; j < 8; ++j) {
            acc.x = fmaf(v[j], hv[j].x, acc.x);
            acc.y = fmaf(v[j], hv[j].y, acc.y);
            acc.z = fmaf(v[j], hv[j].z, acc.z);
            acc.w = fmaf(v[j], hv[j].w, acc.w);
        }
    }
    float4 r = make_float4(fmaxf(acc.x, 0.f), fmaxf(acc.y, 0.f),
                           fmaxf(acc.z, 0.f), fmaxf(acc.w, 0.f));
    *(float4*)&h2[(size_t)n * BLH + lane * 4] = r;
}

// ---------------------------------------------------------------------------
// k4: head as register-tiled GEMM.  M=20000 rows (n,b), K=128 (lp,i), N=64 (o).
// Block = 64 rows (32 nodes); thread = 1 row x 16 o in registers.
// W read via wave-uniform global loads (scalar path) — zero LDS traffic for W.
// s_tile [k][row] stride-65 in LDS (conflict-free), reused as hl[o][row].
// ---------------------------------------------------------------------------
__global__ __launch_bounds__(256) void k4_head(
        const float* __restrict__ h2, const float* __restrict__ Wt,
        const float* __restrict__ b_tcn, const float* __restrict__ W_out,
        const float* __restrict__ b_out, float* __restrict__ y) {
    __shared__ float pool[128 * 65];   // 33.3 KB: s_tile, then reused as hl[o*65+row]
    __shared__ float Wo[HH * PP];      // 3 KB
    const int t   = threadIdx.x;
    const int row = t & 63;                                   // row = nn*2 + b
    const int cg  = __builtin_amdgcn_readfirstlane(t >> 6);   // wave-uniform col group
    const int n0  = blockIdx.x * 32;

    for (int idx = t; idx < HH * PP; idx += 256) Wo[idx] = W_out[idx];
    // stage s_tile[k][row] (conflict-free: bank = (65k+row)%32)
    for (int idx = t; idx < 32 * BLH; idx += 256) {
        int nn = idx >> 8, j = idx & 255;
        float v = (n0 + nn < NN) ? h2[(size_t)(n0 + nn) * BLH + j] : 0.f;
        pool[(j & 127) * 65 + nn * 2 + (j >> 7)] = v;
    }
    __syncthreads();

    const float4* Wt4 = (const float4*)Wt;    // Wt[k*64+o] -> float4 idx k*16+o/4
    float acc[16];
#pragma unroll
    for (int j = 0; j < 16; ++j) acc[j] = 0.f;

#pragma unroll 4
    for (int k = 0; k < 128; ++k) {
        float sv = pool[k * 65 + row];
        float4 w0 = Wt4[k * 16 + cg * 4 + 0];   // wave-uniform -> s_load_dwordx4
        float4 w1 = Wt4[k * 16 + cg * 4 + 1];
        float4 w2 = Wt4[k * 16 + cg * 4 + 2];
        float4 w3 = Wt4[k * 16 + cg * 4 + 3];
        acc[ 0] = fmaf(sv, w0.x, acc[ 0]); acc[ 1] = fmaf(sv, w0.y, acc[ 1]);
        acc[ 2] = fmaf(sv, w0.z, acc[ 2]); acc[ 3] = fmaf(sv, w0.w, acc[ 3]);
        acc[ 4] = fmaf(sv, w1.x, acc[ 4]); acc[ 5] = fmaf(sv, w1.y, acc[ 5]);
        acc[ 6] = fmaf(sv, w1.z, acc[ 6]); acc[ 7] = fmaf(sv, w1.w, acc[ 7]);
        acc[ 8] = fmaf(sv, w2.x, acc[ 8]); acc[ 9] = fmaf(sv, w2.y, acc[ 9]);
        acc[10] = fmaf(sv, w2.z, acc[10]); acc[11] = fmaf(sv, w2.w, acc[11]);
        acc[12] = fmaf(sv, w3.x, acc[12]); acc[13] = fmaf(sv, w3.y, acc[13]);
        acc[14] = fmaf(sv, w3.z, acc[14]); acc[15] = fmaf(sv, w3.w, acc[15]);
    }
    __syncthreads();   // all s_tile reads done; pool is reusable

    const float4* bt4 = (const float4*)b_tcn;  // wave-uniform
    float4 b0 = bt4[cg * 4 + 0], b1 = bt4[cg * 4 + 1];
    float4 b2 = bt4[cg * 4 + 2], b3 = bt4[cg * 4 + 3];
    float bt[16] = {b0.x, b0.y, b0.z, b0.w, b1.x, b1.y, b1.z, b1.w,
                    b2.x, b2.y, b2.z, b2.w, b3.x, b3.y, b3.z, b3.w};
#pragma unroll
    for (int j = 0; j < 16; ++j)
        pool[(cg * 16 + j) * 65 + row] = fmaxf(acc[j] + bt[j], 0.f);  // hl[o][row]
    __syncthreads();

    // epilogue: 768 outputs (64 rows x 12 p), 3 per thread
#pragma unroll
    for (int it = 0; it < 3; ++it) {
        int out = t + it * 256;
        int r2 = out & 63, p = out >> 6;       // p wave-uniform
        int n = n0 + (r2 >> 1), b = r2 & 1;
        float yy = b_out[p];
#pragma unroll 8
        for (int o = 0; o < HH; ++o)
            yy = fmaf(pool[o * 65 + r2], Wo[o * PP + p], yy);
        if (n < NN) y[((size_t)(b * PP + p)) * NN + n] = yy;
    }
}

// ---------------------------------------------------------------------------
extern "C" void kernel_launch(void* const* d_in, const int* in_sizes, int n_in,
                              void* d_out, int out_size, void* d_ws, size_t ws_size,
                              hipStream_t stream) {
    const float* x     = (const float*)d_in[0];
    const int*   row   = (const int*)d_in[1];
    const int*   col   = (const int*)d_in[2];
    const float* vals  = (const float*)d_in[3];
    const float* W_in  = (const float*)d_in[4];
    const float* b_in  = (const float*)d_in[5];
    const float* W_tcn = (const float*)d_in[6];
    const float* b_tcn = (const float*)d_in[7];
    const float* W_out = (const float*)d_in[8];
    const float* b_out = (const float*)d_in[9];
    float* y = (float*)d_out;

    char* ws = (char*)d_ws;
    float* hsmall = (float*)(ws);                    // 10,240,000 B
    int*   deg    = (int*)(ws + 10240000);           //     40,000 B
    int2*  bucket = (int2*)(ws + 10280000);          //  5,120,000 B
    float* h2     = (float*)(ws + 15400000);         // 10,240,000 B
    float* Wt     = (float*)(ws + 25640000);         //     32,768 B

    k1_input_proj<<<NN, 256, 0, stream>>>(x, W_in, b_in, hsmall, deg, bucket);
    k2_build<<<(EE + 3 * HH * HH + 255) / 256, 256, 0, stream>>>(
        row, col, vals, deg, bucket, W_tcn, Wt);
    k3_gather<<<NN / 4, 256, 0, stream>>>(hsmall, deg, bucket, h2);
    // 32 nodes (64 rows) per block -> ceil(NN/32) = 313 blocks  [round-4 bug: was 79]
    k4_head<<<(NN + 31) / 32, 256, 0, stream>>>(h2, Wt, b_tcn, W_out, b_out, y);
}

// Round 7
// 121.606 us; speedup vs baseline: 1.1912x; 1.0506x over previous
//
#include <hip/hip_runtime.h>

// Problem constants: B=2, L=16, N=10000, FIN=8, H=64, P=12, E=80000, K=3
#define NN   10000
#define LL   16
#define FINC 8
#define HH   64
#define PP   12
#define EE   80000
#define BLH  256   // (b,lp,h) = 2*2*64 — only l=14,15 feed out[:,:,-1] (K=3, pad=1)
#define CAP  64    // per-row edge bucket capacity; E/N = 8, P(deg>64) ~ 0

// ---------------------------------------------------------------------------
// k1: input projection at l in {14,15} + zero deg.
// (bucket is NOT pre-zeroed — k3 masks invalid entries instead.)
// ---------------------------------------------------------------------------
__global__ __launch_bounds__(256) void k1_input_proj(
        const float* __restrict__ x, const float* __restrict__ W_in,
        const float* __restrict__ b_in, float* __restrict__ hsmall,
        int* __restrict__ deg) {
    __shared__ float xs[32];
    __shared__ float ws[FINC * HH];
    __shared__ float bs[HH];
    const int n = blockIdx.x;
    const int t = threadIdx.x;
    ws[t]       = W_in[t];
    ws[t + 256] = W_in[t + 256];
    if (t < HH) bs[t] = b_in[t];
    if (t == 0) deg[n] = 0;
    if (t < 32) {
        int bl = t >> 3, f = t & 7;
        int b = bl >> 1, lp = bl & 1;
        xs[t] = x[(((size_t)(b * LL + 14 + lp)) * NN + n) * FINC + f];
    }
    __syncthreads();
    const int h  = t & 63;
    const int bl = t >> 6;
    float acc = bs[h];
#pragma unroll
    for (int f = 0; f < FINC; ++f)
        acc = fmaf(xs[bl * 8 + f], ws[f * HH + h], acc);
    hsmall[(size_t)n * BLH + t] = fmaxf(acc, 0.f);
}

// ---------------------------------------------------------------------------
// k2: bucketed CSR build + pack W_tcn taps {0,1} into Wt[k][o] (k = lp*64+i).
// ---------------------------------------------------------------------------
__global__ __launch_bounds__(256) void k2_build(
        const int* __restrict__ row, const int* __restrict__ col,
        const float* __restrict__ vals, int* __restrict__ deg,
        int2* __restrict__ bucket, const float* __restrict__ W_tcn,
        float* __restrict__ Wt) {
    int e = blockIdx.x * 256 + threadIdx.x;
    if (e < EE) {
        int r = row[e];
        int pos = atomicAdd(&deg[r], 1);
        if (pos < CAP)
            bucket[(size_t)r * CAP + pos] = make_int2(col[e], __float_as_int(vals[e]));
    } else if (e < EE + 3 * HH * HH) {
        int f = e - EE;                 // linear index into W_tcn [o][i][k3]
        int kk = f % 3;
        if (kk < 2) {
            int o = f / (HH * 3);
            int i = (f / 3) % HH;
            Wt[(kk * HH + i) * HH + o] = W_tcn[f];
        }
    }
}

// ---------------------------------------------------------------------------
// k3: gather-aggregate, zero LDS. One wave per node; metadata via one
// coalesced 512B load + shfl broadcast (entries >= deg masked to {0, 0.0});
// 8 independent row loads in flight.
// ---------------------------------------------------------------------------
__global__ __launch_bounds__(256) void k3_gather(
        const float* __restrict__ hsmall, const int* __restrict__ deg,
        const int2* __restrict__ bucket, float* __restrict__ h2) {
    const int wave = threadIdx.x >> 6;
    const int lane = threadIdx.x & 63;
    const int n = blockIdx.x * 4 + wave;
    const int dn  = min(deg[n], CAP);
    const int dnp = (dn + 7) & ~7;
    const int2 meta = bucket[(size_t)n * CAP + lane];   // poison beyond dn — masked

    float4 acc = make_float4(0.f, 0.f, 0.f, 0.f);
    for (int i = 0; i < dnp; i += 8) {
        int   c[8];
        float v[8];
#pragma unroll
        for (int j = 0; j < 8; ++j) {
            int idx = i + j;
            int   cc = __shfl(meta.x, idx);
            float vv = __int_as_float(__shfl(meta.y, idx));
            bool ok = idx < dn;
            c[j] = ok ? cc : 0;
            v[j] = ok ? vv : 0.f;
        }
        float4 hv[8];
#pragma unroll
        for (int j = 0; j < 8; ++j)
            hv[j] = *(const float4*)&hsmall[(size_t)c[j] * BLH + lane * 4];
#pragma unroll
        for (int j = 0; j < 8; ++j) {
            acc.x = fmaf(v[j], hv[j].x, acc.x);
            acc.y = fmaf(v[j], hv[j].y, acc.y);
            acc.z = fmaf(v[j], hv[j].z, acc.z);
            acc.w = fmaf(v[j], hv[j].w, acc.w);
        }
    }
    float4 r = make_float4(fmaxf(acc.x, 0.f), fmaxf(acc.y, 0.f),
                           fmaxf(acc.z, 0.f), fmaxf(acc.w, 0.f));
    *(float4*)&h2[(size_t)n * BLH + lane * 4] = r;
}

// ---------------------------------------------------------------------------
// k4: head GEMM, split-K x2 in-block.  M=20000 rows (n,b), K=128, N=64 (o).
// 512 threads = 64 rows x 4 col-groups x 2 K-halves; thread = 1 row x 16 o
// over 64 k.  W via wave-uniform scalar loads; s_tile [k][row] stride-65;
// cross-half reduction through stride-17 LDS; pool reused as hl[o][row].
// ---------------------------------------------------------------------------
__global__ __launch_bounds__(512) void k4_head(
        const float* __restrict__ h2, const float* __restrict__ Wt,
        const float* __restrict__ b_tcn, const float* __restrict__ W_out,
        const float* __restrict__ b_out, float* __restrict__ y) {
    __shared__ float pool[128 * 65];   // 33.3 KB: s_tile, then hl[o*65+row]
    __shared__ float red[256 * 17];    // 17.4 KB: kq=1 partials, padded
    __shared__ float Wo[HH * PP];      // 3 KB
    const int t   = threadIdx.x;       // 0..511
    const int row = t & 63;
    const int cg  = __builtin_amdgcn_readfirstlane((t >> 6) & 3);  // wave-uniform
    const int kq  = __builtin_amdgcn_readfirstlane(t >> 8);        // wave-uniform
    const int n0  = blockIdx.x * 32;

    for (int idx = t; idx < HH * PP; idx += 512) Wo[idx] = W_out[idx];
    // stage s_tile[k][row] (conflict-free: bank = (65k+row)%32)
    for (int idx = t; idx < 32 * BLH; idx += 512) {
        int nn = idx >> 8, j = idx & 255;
        float v = (n0 + nn < NN) ? h2[(size_t)(n0 + nn) * BLH + j] : 0.f;
        pool[(j & 127) * 65 + nn * 2 + (j >> 7)] = v;
    }
    __syncthreads();

    const float4* Wt4 = (const float4*)Wt;    // Wt[k*64+o] -> float4 idx k*16+o/4
    float acc[16];
#pragma unroll
    for (int j = 0; j < 16; ++j) acc[j] = 0.f;

    const int kbase = kq * 64;
#pragma unroll 4
    for (int kk = 0; kk < 64; ++kk) {
        const int k = kbase + kk;
        float sv = pool[k * 65 + row];
        float4 w0 = Wt4[k * 16 + cg * 4 + 0];   // wave-uniform -> s_load_dwordx4
        float4 w1 = Wt4[k * 16 + cg * 4 + 1];
        float4 w2 = Wt4[k * 16 + cg * 4 + 2];
        float4 w3 = Wt4[k * 16 + cg * 4 + 3];
        acc[ 0] = fmaf(sv, w0.x, acc[ 0]); acc[ 1] = fmaf(sv, w0.y, acc[ 1]);
        acc[ 2] = fmaf(sv, w0.z, acc[ 2]); acc[ 3] = fmaf(sv, w0.w, acc[ 3]);
        acc[ 4] = fmaf(sv, w1.x, acc[ 4]); acc[ 5] = fmaf(sv, w1.y, acc[ 5]);
        acc[ 6] = fmaf(sv, w1.z, acc[ 6]); acc[ 7] = fmaf(sv, w1.w, acc[ 7]);
        acc[ 8] = fmaf(sv, w2.x, acc[ 8]); acc[ 9] = fmaf(sv, w2.y, acc[ 9]);
        acc[10] = fmaf(sv, w2.z, acc[10]); acc[11] = fmaf(sv, w2.w, acc[11]);
        acc[12] = fmaf(sv, w3.x, acc[12]); acc[13] = fmaf(sv, w3.y, acc[13]);
        acc[14] = fmaf(sv, w3.z, acc[14]); acc[15] = fmaf(sv, w3.w, acc[15]);
    }
    // kq=1 partials -> LDS (stride 17: odd stride, 2 lanes/bank = free)
    if (kq == 1) {
#pragma unroll
        for (int j = 0; j < 16; ++j) red[(t - 256) * 17 + j] = acc[j];
    }
    __syncthreads();   // also: all s_tile reads done; pool reusable

    if (kq == 0) {
        const float4* bt4 = (const float4*)b_tcn;   // wave-uniform scalar loads
        float4 b0 = bt4[cg * 4 + 0], b1 = bt4[cg * 4 + 1];
        float4 b2 = bt4[cg * 4 + 2], b3 = bt4[cg * 4 + 3];
        float bt[16] = {b0.x, b0.y, b0.z, b0.w, b1.x, b1.y, b1.z, b1.w,
                        b2.x, b2.y, b2.z, b2.w, b3.x, b3.y, b3.z, b3.w};
#pragma unroll
        for (int j = 0; j < 16; ++j) {
            float s2 = acc[j] + red[t * 17 + j];
            pool[(cg * 16 + j) * 65 + row] = fmaxf(s2 + bt[j], 0.f);  // hl[o][row]
        }
    }
    __syncthreads();

    // epilogue: 768 outputs = 64 rows (n,b already encoded) x 12 p
    // [round-6 bug: bound was 2*PP*64=1536 -> p ran 12..23, clobbered b=1 half]
    for (int out = t; out < 64 * PP; out += 512) {
        int r2 = out & 63, p = out >> 6;       // p in 0..11
        int n = n0 + (r2 >> 1), b = r2 & 1;
        float yy = b_out[p];
#pragma unroll 8
        for (int o = 0; o < HH; ++o)
            yy = fmaf(pool[o * 65 + r2], Wo[o * PP + p], yy);
        if (n < NN) y[((size_t)(b * PP + p)) * NN + n] = yy;
    }
}

// ---------------------------------------------------------------------------
extern "C" void kernel_launch(void* const* d_in, const int* in_sizes, int n_in,
                              void* d_out, int out_size, void* d_ws, size_t ws_size,
                              hipStream_t stream) {
    const float* x     = (const float*)d_in[0];
    const int*   row   = (const int*)d_in[1];
    const int*   col   = (const int*)d_in[2];
    const float* vals  = (const float*)d_in[3];
    const float* W_in  = (const float*)d_in[4];
    const float* b_in  = (const float*)d_in[5];
    const float* W_tcn = (const float*)d_in[6];
    const float* b_tcn = (const float*)d_in[7];
    const float* W_out = (const float*)d_in[8];
    const float* b_out = (const float*)d_in[9];
    float* y = (float*)d_out;

    char* ws = (char*)d_ws;
    float* hsmall = (float*)(ws);                    // 10,240,000 B
    int*   deg    = (int*)(ws + 10240000);           //     40,000 B
    int2*  bucket = (int2*)(ws + 10280000);          //  5,120,000 B
    float* h2     = (float*)(ws + 15400000);         // 10,240,000 B
    float* Wt     = (float*)(ws + 25640000);         //     32,768 B

    k1_input_proj<<<NN, 256, 0, stream>>>(x, W_in, b_in, hsmall, deg);
    k2_build<<<(EE + 3 * HH * HH + 255) / 256, 256, 0, stream>>>(
        row, col, vals, deg, bucket, W_tcn, Wt);
    k3_gather<<<NN / 4, 256, 0, stream>>>(hsmall, deg, bucket, h2);
    // 32 nodes (64 rows) per block, 512 threads (split-K x2) -> 313 blocks
    k4_head<<<(NN + 31) / 32, 512, 0, stream>>>(h2, Wt, b_tcn, W_out, b_out, y);
}